// Round 10
// baseline (256.541 us; speedup 1.0000x reference)
//
#include <hip/hip_runtime.h>
#include <hip/hip_bf16.h>
#include <math.h>

#define NPTS 30000
#define KNN  16
#define NB   30          // batches (of 2 points) per block
#define GRID 500         // 500 * 60 pts = 30000 exactly

typedef __attribute__((ext_vector_type(8)))  __bf16 bf16x8;
typedef __attribute__((ext_vector_type(16))) float  f32x16;
typedef __attribute__((ext_vector_type(4)))  float  f32x4;

__device__ __forceinline__ unsigned short f2bf(float x) {
    __bf16 b = (__bf16)x;                       // native cvt (RNE)
    return __builtin_bit_cast(unsigned short, b);
}
__device__ __forceinline__ unsigned pk2(float a, float b) {
    return (unsigned)f2bf(a) | ((unsigned)f2bf(b) << 16);
}
__device__ __forceinline__ float bf_lo(unsigned u) { return __builtin_bit_cast(float, u << 16); }
__device__ __forceinline__ float bf_hi(unsigned u) { return __builtin_bit_cast(float, u & 0xffff0000u); }
// tanh-form GELU: x*(1 - 1/(exp(1.5958*(x+0.044715x^3)) + 1))
__device__ __forceinline__ float gelu_t(float x) {
    float x2 = x * x;
    float u  = x * fmaf(0.07135481624f, x2, 1.59576912161f);
    float e  = __expf(u);
    float r  = __builtin_amdgcn_rcpf(e + 1.0f);
    return fmaf(-x, r, x);
}

// ---- prep: bf16 weight layouts in ws (identical to R7) ----
// w1dt[d][k] = W1[128+k][d]          (256x128)
// w2t [e][c] = W2[c][e]              (256x256)
// wcst[col][k] = col<256 ? W1[k][col] : Ws[k][col-256]   (512x128)
__global__ void prep_w(const float* __restrict__ W1, const float* __restrict__ W2,
                       const float* __restrict__ Ws,
                       unsigned short* __restrict__ w1dt, unsigned short* __restrict__ w2t,
                       unsigned short* __restrict__ wcst) {
    int t = blockIdx.x * 256 + threadIdx.x;          // t < 65536
    {   int e = t >> 8, c = t & 255;
        w2t[t] = f2bf(W2[c * 256 + e]); }
    {   int col = t >> 7, k = t & 127;
        float v = (col < 256) ? W1[k * 256 + col] : Ws[k * 256 + (col - 256)];
        wcst[t] = f2bf(v); }
    if (t < 32768) {
        int d = t >> 7, k = t & 127;
        w1dt[t] = f2bf(W1[(128 + k) * 256 + d]); }
}

// R7's proven single-barrier pipeline at BP=2 (32 edge rows/iter) -> LDS 68 KB ->
// 2 blocks/CU = 4 waves/SIMD (R5/R7 showed 128-VGPR no-spill fit for this live set).
// Per iter i (one barrier at end):
//   B) GEMM2(i-1): h[(i-1)&1] -> agg[(i-1)&1]
//   C) GEMM1(i):   edge[i&1] + c2[(i>>2)&1] -> h[i&1]
//   D) LN(i-2):    agg[(i-2)&1] + c2 skip -> out
//   E) c2pass((i>>2)+1) at (i&3)==2 -> c2[((i>>2)+1)&1]
//   F) stage(i+1) -> edge[(i+1)&1]   (immediate load+write; TLP hides gather)
// Lifetimes (all >=1 barrier producer->consumer; re-writes >=2 phases after last read):
//   edge[p]: W @F(i-1) -> R @C(i) -> next W @F(i+1). h[p]: W @C(i) -> R @B(i+1) -> W @C(i+2).
//   agg[p]: W @B(p+1) -> R @D(p+2) -> W @B(p+3). c2[s&1]: W @E(4s-2) -> R @C(4s..4s+3),
//   @D(4s+2..4s+5) -> next W @E(4s+6).
__global__ __launch_bounds__(512) void edgeconv_main(
    const float* __restrict__ feat, const int* __restrict__ knn,
    const unsigned short* __restrict__ w1dt, const unsigned short* __restrict__ w2t,
    const unsigned short* __restrict__ wcst,
    const float* __restrict__ b1, const float* __restrict__ b2,
    const float* __restrict__ bs,
    const float* __restrict__ gamma, const float* __restrict__ beta,
    float* __restrict__ out)
{
    __shared__ __align__(16) unsigned char  s_edge[2][32 * 256];   // 16 KB diff-edge bf16, swz (row&15)<<4
    __shared__ __align__(16) unsigned char  s_h[2][32 * 512];      // 32 KB h bf16, swz (row&31)<<4
    __shared__ __align__(16) unsigned short s_c2[2][8][512];       // 16 KB [buf][pt-in-super8][cterm|skip]
    __shared__ __align__(16) float s_agg[2][2][256];               //  4 KB channel max
    // total 68 KB -> 2 blocks/CU

    const int lane = threadIdx.x & 63;
    const int wv   = threadIdx.x >> 6;      // 0..7
    const int l31  = lane & 31;
    const int lh   = lane >> 5;
    const int l15  = lane & 15;
    const int l4   = lane >> 4;
    const int pblock = blockIdx.x * 60;
    const int chb = wv * 32;                // this wave's 32 channels (both GEMMs)

    // persistent weight fragments: 96 VGPR (proven no-spill at 128 alloc in R5-R7)
    bf16x8 w1f[8], w2f[16];
    #pragma unroll
    for (int ks = 0; ks < 8; ++ks)
        w1f[ks] = *(const bf16x8*)(w1dt + (chb + l31) * 128 + ks * 16 + lh * 8);
    #pragma unroll
    for (int ks = 0; ks < 16; ++ks)
        w2f[ks] = *(const bf16x8*)(w2t + (chb + l31) * 256 + ks * 16 + lh * 8);

    // c2-pass for 8-point super s: cterm+b1 (cols 0:256) | skip+bs+b2 (256:512)
    auto c2pass = [&](int s) {
        const int buf = s & 1;
        bf16x8 af[4];
        #pragma unroll
        for (int ks = 0; ks < 4; ++ks) {
            int pi = s * 8 + (l15 & 7);                // A rows 8-15 dup 0-7 (never read)
            if (pi > 59) pi = 59;                      // clamp (super 7: pts 60-63 absent)
            const float* fp = feat + (long)(pblock + pi) * 128 + ks * 32 + l4 * 8;
            float4 f0 = *(const float4*)fp;
            float4 f1 = *(const float4*)(fp + 4);
            uint4 u;
            u.x = pk2(f0.x, f0.y); u.y = pk2(f0.z, f0.w);
            u.z = pk2(f1.x, f1.y); u.w = pk2(f1.z, f1.w);
            af[ks] = __builtin_bit_cast(bf16x8, u);
        }
        #pragma unroll
        for (int j = 0; j < 4; ++j) {
            const int ct  = wv * 4 + j;                // 0..31
            const int col = ct * 16 + l15;
            float bias = (ct < 16) ? b1[col] : (bs[col - 256] + b2[col - 256]);
            f32x4 acc = {bias, bias, bias, bias};
            #pragma unroll
            for (int ks = 0; ks < 4; ++ks) {
                bf16x8 bf = *(const bf16x8*)(wcst + col * 128 + ks * 32 + l4 * 8);
                acc = __builtin_amdgcn_mfma_f32_16x16x32_bf16(af[ks], bf, acc, 0, 0, 0);
            }
            #pragma unroll
            for (int r = 0; r < 4; ++r) {
                int prow = l4 * 4 + r;                 // D row = point-in-super
                if (prow < 8) s_c2[buf][prow][col] = f2bf(acc[r]);
            }
        }
    };

    // stage batch bt into edge[bt&1]: wave loads+writes 4 rows (immediate)
    auto stage = [&](int bt) {
        const int st_pt = wv >> 2;                     // 0..1
        const int st_kb = (wv & 3) * 4;
        const int n = pblock + bt * 2 + st_pt;
        float2 cc = *(const float2*)(feat + (long)n * 128 + lane * 2);
        int idx[4];
        #pragma unroll
        for (int kk = 0; kk < 4; ++kk) idx[kk] = knn[n * 16 + st_kb + kk];
        #pragma unroll
        for (int kk = 0; kk < 4; ++kk) {
            float2 nb = *(const float2*)(feat + (long)idx[kk] * 128 + lane * 2);
            int row = st_pt * 16 + st_kb + kk;
            unsigned v = pk2(nb.x - cc.x, nb.y - cc.y);
            *(unsigned*)(s_edge[bt & 1] + row * 256 + ((unsigned)(lane * 4) ^ (unsigned)((row & 15) << 4))) = v;
        }
    };

    // ---- prologue ----
    stage(0);
    c2pass(0);
    __syncthreads();

    const f32x16 z16 = (f32x16)0.0f;

    #pragma unroll 1
    for (int i = 0; i <= NB + 1; ++i) {
        // ---- B) GEMM2(i-1): eo = h . W2; max over each point's 16 rows -> s_agg ----
        if (i >= 1 && i <= NB) {
            const int bt = i - 1;
            const int row = l31;
            const unsigned swz = (unsigned)((row & 31) << 4);
            const unsigned rb = (unsigned)row * 512u;
            f32x16 a2 = z16;
            #pragma unroll
            for (int ks = 0; ks < 16; ++ks) {
                bf16x8 hf = *(const bf16x8*)(s_h[bt & 1] + rb + ((unsigned)(ks * 32 + lh * 16) ^ swz));
                a2 = __builtin_amdgcn_mfma_f32_32x32x16_bf16(hf, w2f[ks], a2, 0, 0, 0);
            }
            float m0 = a2[0], m1 = a2[8];
            #pragma unroll
            for (int r = 1; r < 8; ++r) {
                m0 = fmaxf(m0, a2[r]);        // regs 0-7  = h rows 0..15  (point 0)
                m1 = fmaxf(m1, a2[8 + r]);    // regs 8-15 = h rows 16..31 (point 1)
            }
            m0 = fmaxf(m0, __shfl_xor(m0, 32));
            m1 = fmaxf(m1, __shfl_xor(m1, 32));
            if (lh == 0) {
                s_agg[bt & 1][0][chb + l31] = m0;
                s_agg[bt & 1][1][chb + l31] = m1;
            }
        }

        // ---- C) GEMM1(i): h = gelu(edge_diff . W1d + cterm) -> s_h[i&1] ----
        if (i < NB) {
            const int sB = (i >> 2) & 1;
            const int row = l31;
            f32x16 acc1 = z16;
            {
                const unsigned swz = (unsigned)((row & 15) << 4);
                const unsigned rb = (unsigned)row * 256u;
                #pragma unroll
                for (int ks = 0; ks < 8; ++ks) {
                    bf16x8 bf = *(const bf16x8*)(s_edge[i & 1] + rb + ((unsigned)(ks * 32 + lh * 16) ^ swz));
                    acc1 = __builtin_amdgcn_mfma_f32_32x32x16_bf16(w1f[ks], bf, acc1, 0, 0, 0);
                }
            }
            {
                const int pt8 = (i & 3) * 2 + (l31 >> 4);
                const unsigned swz = (unsigned)((row & 31) << 4);
                #pragma unroll
                for (int g = 0; g < 4; ++g) {
                    const int ch0 = chb + 8 * g + 4 * lh;
                    uint2 c2v = *(const uint2*)(&s_c2[sB][pt8][ch0]);   // broadcast read
                    float v0 = gelu_t(acc1[4 * g + 0] + bf_lo(c2v.x));
                    float v1 = gelu_t(acc1[4 * g + 1] + bf_hi(c2v.x));
                    float v2 = gelu_t(acc1[4 * g + 2] + bf_lo(c2v.y));
                    float v3 = gelu_t(acc1[4 * g + 3] + bf_hi(c2v.y));
                    uint2 hv; hv.x = pk2(v0, v1); hv.y = pk2(v2, v3);
                    *(uint2*)(s_h[i & 1] + (unsigned)row * 512u + ((unsigned)(ch0 * 2) ^ swz)) = hv;
                }
            }
        }

        // ---- D) LayerNorm(i-2) on waves 0-1 (one point each) ----
        if (i >= 2 && wv < 2) {
            const int bt2 = i - 2;
            const int n   = pblock + bt2 * 2 + wv;
            const int sB  = (bt2 >> 2) & 1;
            const int pt8 = (bt2 & 3) * 2 + wv;
            float4 ag = *(const float4*)&s_agg[bt2 & 1][wv][lane * 4];
            uint2 sk  = *(const uint2*)(&s_c2[sB][pt8][256 + lane * 4]);
            float x0 = ag.x + bf_lo(sk.x), x1 = ag.y + bf_hi(sk.x);
            float x2 = ag.z + bf_lo(sk.y), x3 = ag.w + bf_hi(sk.y);
            float s  = x0 + x1 + x2 + x3;
            float ss = fmaf(x0, x0, fmaf(x1, x1, fmaf(x2, x2, x3 * x3)));
            #pragma unroll
            for (int off = 1; off < 64; off <<= 1) {
                s  += __shfl_xor(s, off);
                ss += __shfl_xor(ss, off);
            }
            float mu   = s * (1.0f / 256.0f);
            float var  = ss * (1.0f / 256.0f) - mu * mu;
            float rstd = rsqrtf(var + 1e-5f);
            float4 g4 = *(const float4*)&gamma[lane * 4];
            float4 b4 = *(const float4*)&beta[lane * 4];
            float4 o;
            o.x = (x0 - mu) * rstd * g4.x + b4.x;
            o.y = (x1 - mu) * rstd * g4.y + b4.y;
            o.z = (x2 - mu) * rstd * g4.z + b4.z;
            o.w = (x3 - mu) * rstd * g4.w + b4.w;
            *(float4*)&out[(long)n * 256 + lane * 4] = o;
        }

        // ---- E) c2 super s=(i>>2)+1 at i=4s-2 ----
        if ((i & 3) == 2) {
            int s = (i >> 2) + 1;
            if (s < 8) c2pass(s);
        }

        // ---- F) stage batch i+1 -> edge[(i+1)&1] ----
        if (i + 1 < NB) stage(i + 1);

        __syncthreads();
    }
}

extern "C" void kernel_launch(void* const* d_in, const int* in_sizes, int n_in,
                              void* d_out, int out_size, void* d_ws, size_t ws_size,
                              hipStream_t stream) {
    const float* feat  = (const float*)d_in[0];
    const int*   knn   = (const int*)  d_in[1];
    const float* W1    = (const float*)d_in[2];
    const float* b1    = (const float*)d_in[3];
    const float* W2    = (const float*)d_in[4];
    const float* b2    = (const float*)d_in[5];
    const float* Ws    = (const float*)d_in[6];
    const float* bs    = (const float*)d_in[7];
    const float* gamma = (const float*)d_in[8];
    const float* beta  = (const float*)d_in[9];
    float* out = (float*)d_out;

    unsigned short* w1dt = (unsigned short*)d_ws;          //  64 KB
    unsigned short* w2t  = w1dt + 32768;                   // 128 KB
    unsigned short* wcst = w2t + 65536;                    // 128 KB  (total 320 KB)

    hipLaunchKernelGGL(prep_w, dim3(256), dim3(256), 0, stream, W1, W2, Ws, w1dt, w2t, wcst);
    hipLaunchKernelGGL(edgeconv_main, dim3(GRID), dim3(512), 0, stream,
                       feat, knn, w1dt, w2t, wcst, b1, b2, bs, gamma, beta, out);
}